// Round 1
// baseline (293.839 us; speedup 1.0000x reference)
//
#include <hip/hip_runtime.h>

static constexpr int B = 4;
static constexpr int N = 8192;
static constexpr int H = 8;
static constexpr int D = 64;
static constexpr int BH = B * H;   // 32
#define EPSF 1e-6f

__device__ __forceinline__ float featmap(float x) {
    // elu(x)+1 : x>0 -> x+1 ; else exp(x)
    return x > 0.0f ? (x + 1.0f) : __expf(x);
}

// ---------------------------------------------------------------------------
// Pass 1: KV[bh][m][d] = sum_n f(K)[n][d]*V[n][m];  Ksum[bh][d] = sum_n f(K)[n][d]
// grid (BH, 32), block 256. Each block: 256 rows (8 stages x 32 rows),
// accumulates a full 64x64 tile in registers (4x4 per thread), atomics at end.
// ---------------------------------------------------------------------------
__global__ __launch_bounds__(256, 4) void kv_accum_kernel(
    const float* __restrict__ keys,
    const float* __restrict__ values,
    const float* __restrict__ mask,
    float* __restrict__ kv,     // [BH][64][64]  (m, d)
    float* __restrict__ ksum)   // [BH][64]
{
    const int bh = blockIdx.x;
    const int b  = bh >> 3;
    const int h  = bh & 7;
    const int t  = threadIdx.x;
    const int td = t & 15;   // d-group (4 d's)
    const int tm = t >> 4;   // m-group (4 m's)
    const int nbase = blockIdx.y * 256;

    __shared__ float Ks[32][64];
    __shared__ float Vs[32][64];

    float acc[4][4] = {};
    float ksacc[4] = {0.f, 0.f, 0.f, 0.f};
    const bool do_ks = (t < 64);   // wave-uniform: only wave 0 accumulates ksum

    for (int stage = 0; stage < 8; ++stage) {
        const int n0 = nbase + stage * 32;
        __syncthreads();
        #pragma unroll
        for (int l = 0; l < 2; ++l) {
            const int idx = t + l * 256;       // 0..511
            const int row = idx >> 4;          // 0..31
            const int cv  = idx & 15;          // float4 column
            const int n = n0 + row;
            const size_t g = ((size_t)((b * N + n) * H + h)) * D + cv * 4;
            const float4 kq = *(const float4*)(keys + g);
            const float4 vq = *(const float4*)(values + g);
            const float mk = mask[b * N + n];
            float4 kf;
            kf.x = featmap(kq.x) * mk;
            kf.y = featmap(kq.y) * mk;
            kf.z = featmap(kq.z) * mk;
            kf.w = featmap(kq.w) * mk;
            *(float4*)&Ks[row][cv * 4] = kf;
            *(float4*)&Vs[row][cv * 4] = vq;
        }
        __syncthreads();
        #pragma unroll 2
        for (int n = 0; n < 32; ++n) {
            const float4 kq = *(const float4*)&Ks[n][td * 4];
            const float4 vq = *(const float4*)&Vs[n][tm * 4];
            const float kk[4] = {kq.x, kq.y, kq.z, kq.w};
            const float vv[4] = {vq.x, vq.y, vq.z, vq.w};
            #pragma unroll
            for (int i = 0; i < 4; ++i) {
                #pragma unroll
                for (int jj = 0; jj < 4; ++jj)
                    acc[i][jj] += vv[i] * kk[jj];
            }
            if (do_ks) {
                ksacc[0] += kk[0]; ksacc[1] += kk[1];
                ksacc[2] += kk[2]; ksacc[3] += kk[3];
            }
        }
    }

    float* kvb = kv + (size_t)bh * 4096;
    #pragma unroll
    for (int i = 0; i < 4; ++i) {
        const int m = tm * 4 + i;
        #pragma unroll
        for (int jj = 0; jj < 4; ++jj)
            atomicAdd(kvb + m * 64 + td * 4 + jj, acc[i][jj]);
    }
    if (t < 16) {   // tm == 0 wave-0 threads hold complete ksum partials
        #pragma unroll
        for (int jj = 0; jj < 4; ++jj)
            atomicAdd(ksum + bh * 64 + td * 4 + jj, ksacc[jj]);
    }
}

// ---------------------------------------------------------------------------
// Pass 2: out[b,n,h,m] = (sum_d f(Q)[n][d]*KV[m][d]) / (sum_d f(Q)[n][d]*Ksum[d] + eps)
// grid (BH, 32), block 256. Each block: 256 rows (4 tiles x 64 rows).
// KV is staged transposed (KVT[d][m]) once per block; Q tile staged row-major.
// Thread (i = t>>4, j = t&15) computes rows i*4..+3, cols j*4..+3.
// ---------------------------------------------------------------------------
__global__ __launch_bounds__(256, 4) void out_kernel(
    const float* __restrict__ queries,
    const float* __restrict__ kv,
    const float* __restrict__ ksum,
    float* __restrict__ out)
{
    const int bh = blockIdx.x;
    const int b  = bh >> 3;
    const int h  = bh & 7;
    const int t  = threadIdx.x;
    const int j  = t & 15;   // m-group
    const int i  = t >> 4;   // n-group (0..15)
    const int nbase = blockIdx.y * 256;

    // pad 68 keeps float4 rows 16B-aligned (68%4==0) and conflicts <=2-way
    __shared__ float Qs[64][68];
    __shared__ float KVT[64][68];
    __shared__ float KS[64];

    // stage KVT (transposed) and KS once per block
    #pragma unroll
    for (int l = 0; l < 4; ++l) {
        const int idx = t + l * 256;   // 0..1023
        const int m = idx >> 4;
        const int c = idx & 15;
        const float4 v = *(const float4*)(kv + (size_t)bh * 4096 + m * 64 + c * 4);
        KVT[c * 4 + 0][m] = v.x;
        KVT[c * 4 + 1][m] = v.y;
        KVT[c * 4 + 2][m] = v.z;
        KVT[c * 4 + 3][m] = v.w;
    }
    if (t < 64) KS[t] = ksum[bh * 64 + t];

    for (int tt = 0; tt < 4; ++tt) {
        const int r0 = nbase + tt * 64;
        __syncthreads();   // covers KVT/KS on tt==0, protects Qs afterwards
        #pragma unroll
        for (int l = 0; l < 4; ++l) {
            const int idx = t + l * 256;
            const int r = idx >> 4;
            const int c = idx & 15;
            const int n = r0 + r;
            const float4 q = *(const float4*)(queries + ((size_t)((b * N + n) * H + h)) * D + c * 4);
            float4 qf;
            qf.x = featmap(q.x); qf.y = featmap(q.y);
            qf.z = featmap(q.z); qf.w = featmap(q.w);
            *(float4*)&Qs[r][c * 4] = qf;
        }
        __syncthreads();

        float acc[4][4] = {};
        float zacc[4] = {0.f, 0.f, 0.f, 0.f};
        for (int dc = 0; dc < 64; dc += 4) {
            const float4 q0 = *(const float4*)&Qs[i * 4 + 0][dc];
            const float4 q1 = *(const float4*)&Qs[i * 4 + 1][dc];
            const float4 q2 = *(const float4*)&Qs[i * 4 + 2][dc];
            const float4 q3 = *(const float4*)&Qs[i * 4 + 3][dc];
            const float4 k0 = *(const float4*)&KVT[dc + 0][j * 4];
            const float4 k1 = *(const float4*)&KVT[dc + 1][j * 4];
            const float4 k2 = *(const float4*)&KVT[dc + 2][j * 4];
            const float4 k3 = *(const float4*)&KVT[dc + 3][j * 4];
            const float4 ks4 = *(const float4*)&KS[dc];

            const float qv[4][4] = {{q0.x, q0.y, q0.z, q0.w},
                                    {q1.x, q1.y, q1.z, q1.w},
                                    {q2.x, q2.y, q2.z, q2.w},
                                    {q3.x, q3.y, q3.z, q3.w}};
            const float kf[4][4] = {{k0.x, k0.y, k0.z, k0.w},
                                    {k1.x, k1.y, k1.z, k1.w},
                                    {k2.x, k2.y, k2.z, k2.w},
                                    {k3.x, k3.y, k3.z, k3.w}};
            const float ksv[4] = {ks4.x, ks4.y, ks4.z, ks4.w};

            #pragma unroll
            for (int dd = 0; dd < 4; ++dd) {
                #pragma unroll
                for (int r = 0; r < 4; ++r) {
                    zacc[r] += qv[r][dd] * ksv[dd];
                    #pragma unroll
                    for (int c = 0; c < 4; ++c)
                        acc[r][c] += qv[r][dd] * kf[dd][c];
                }
            }
        }

        #pragma unroll
        for (int r = 0; r < 4; ++r) {
            const int n = r0 + i * 4 + r;
            const float zinv = 1.0f / (zacc[r] + EPSF);
            float4 o;
            o.x = acc[r][0] * zinv;
            o.y = acc[r][1] * zinv;
            o.z = acc[r][2] * zinv;
            o.w = acc[r][3] * zinv;
            *(float4*)(out + ((size_t)((b * N + n) * H + h)) * D + j * 4) = o;
        }
    }
}

extern "C" void kernel_launch(void* const* d_in, const int* in_sizes, int n_in,
                              void* d_out, int out_size, void* d_ws, size_t ws_size,
                              hipStream_t stream)
{
    const float* q    = (const float*)d_in[0];
    const float* k    = (const float*)d_in[1];
    const float* v    = (const float*)d_in[2];
    const float* mask = (const float*)d_in[3];
    float* out = (float*)d_out;

    float* kv = (float*)d_ws;                       // [BH][64][64]
    float* ks = kv + (size_t)BH * 64 * 64;          // [BH][64]

    hipMemsetAsync(d_ws, 0, (size_t)(BH * 64 * 64 + BH * 64) * sizeof(float), stream);
    kv_accum_kernel<<<dim3(BH, 32), 256, 0, stream>>>(k, v, mask, kv, ks);
    out_kernel<<<dim3(BH, 32), 256, 0, stream>>>(q, kv, ks, out);
}

// Round 2
// 229.552 us; speedup vs baseline: 1.2801x; 1.2801x over previous
//
#include <hip/hip_runtime.h>

static constexpr int B = 4;
static constexpr int N = 8192;
static constexpr int H = 8;
static constexpr int BH = B * H;   // 32
#define EPSF 1e-6f

typedef _Float16 f16;
typedef _Float16 f16x8 __attribute__((ext_vector_type(8)));
typedef float f32x4 __attribute__((ext_vector_type(4)));

__device__ __forceinline__ float featmap(float x) {
    return x > 0.0f ? (x + 1.0f) : __expf(x);   // elu(x)+1
}

union H8 { f16x8 v; unsigned long long u[2]; };
__device__ __forceinline__ f16x8 lds_load8(const f16* p) {
    H8 r;
    r.u[0] = *(const unsigned long long*)(p);
    r.u[1] = *(const unsigned long long*)(p + 4);
    return r.v;
}
__device__ __forceinline__ unsigned pack2(float a, float b) {
    union { f16 h[2]; unsigned u; } x;
    x.h[0] = (f16)a; x.h[1] = (f16)b;
    return x.u;
}
__device__ __forceinline__ unsigned long long pack4(float a, float b, float c, float d) {
    union { f16 h[4]; unsigned long long u; } x;
    x.h[0] = (f16)a; x.h[1] = (f16)b; x.h[2] = (f16)c; x.h[3] = (f16)d;
    return x.u;
}

// ---------------------------------------------------------------------------
// Pass 1 (MFMA): KV[bh][m][d] = sum_n V[n][m]*fK[n][d];  Ksum[bh][d] += sum_n fK[n][d]
// grid (BH, 16), block 256 (4 waves). Each block: 512 rows = 16 K-steps of 32.
// LDS holds transposed fp16 tiles KT[d][n], VT[m][n], double-buffered.
// Wave w computes m-strip [16w,16w+16) x all 64 d via 4 MFMA per K-step.
// ---------------------------------------------------------------------------
static constexpr int S1 = 16;
static constexpr int ROWS1 = N / S1;      // 512
static constexpr int NSTEPS1 = ROWS1 / 32; // 16

__global__ __launch_bounds__(256, 2) void kv_pass(
    const float* __restrict__ keys,
    const float* __restrict__ values,
    const float* __restrict__ mask,
    float* __restrict__ kv,     // [BH][64][64] (m,d) fp32, pre-zeroed
    float* __restrict__ ksum)   // [BH][64] fp32, pre-zeroed
{
    const int bh = blockIdx.x, b = bh >> 3, h = bh & 7;
    const int t = threadIdx.x;
    const int wave = t >> 6, lane = t & 63;
    const int p = t >> 4;          // 0..15: row-pair within K-step
    const int c = t & 15;          // float4 column (d/m group)
    const int quad = lane >> 4;    // 0..3
    const int l15 = lane & 15;
    const int n0 = blockIdx.y * ROWS1;

    __shared__ f16 KT[2][64][36];  // [buf][d][n] pitch 72B: frag reads conflict-free
    __shared__ f16 VT[2][64][36];  // [buf][m][n]
    __shared__ float Ksw[4][64];

    const float* mrow = mask + (size_t)b * N;

    // prefetch step 0
    int n = n0 + 2 * p;
    size_t g0 = ((size_t)((b * N + n) * H + h)) * 64 + c * 4;
    size_t g1 = g0 + (size_t)H * 64;
    float4 kq0 = *(const float4*)(keys + g0);
    float4 kq1 = *(const float4*)(keys + g1);
    float4 vq0 = *(const float4*)(values + g0);
    float4 vq1 = *(const float4*)(values + g1);
    float mk0 = mrow[n], mk1 = mrow[n + 1];

    f32x4 acc[4];
    #pragma unroll
    for (int i = 0; i < 4; ++i) acc[i] = (f32x4){0.f, 0.f, 0.f, 0.f};
    float ksacc[4] = {0.f, 0.f, 0.f, 0.f};

    for (int s = 0; s < NSTEPS1; ++s) {
        const int buf = s & 1;
        // featmap + mask in fp32, accumulate ksum, write fp16 transposed tiles
        const float fk0[4] = {featmap(kq0.x) * mk0, featmap(kq0.y) * mk0,
                              featmap(kq0.z) * mk0, featmap(kq0.w) * mk0};
        const float fk1[4] = {featmap(kq1.x) * mk1, featmap(kq1.y) * mk1,
                              featmap(kq1.z) * mk1, featmap(kq1.w) * mk1};
        const float fv0[4] = {vq0.x, vq0.y, vq0.z, vq0.w};
        const float fv1[4] = {vq1.x, vq1.y, vq1.z, vq1.w};
        #pragma unroll
        for (int dd = 0; dd < 4; ++dd) {
            ksacc[dd] += fk0[dd] + fk1[dd];
            *(unsigned*)&KT[buf][c * 4 + dd][2 * p] = pack2(fk0[dd], fk1[dd]);
            *(unsigned*)&VT[buf][c * 4 + dd][2 * p] = pack2(fv0[dd], fv1[dd]);
        }
        // prefetch next K-step (global only; no LDS dependency)
        if (s + 1 < NSTEPS1) {
            const int nn = n0 + (s + 1) * 32 + 2 * p;
            const size_t h0 = ((size_t)((b * N + nn) * H + h)) * 64 + c * 4;
            const size_t h1 = h0 + (size_t)H * 64;
            kq0 = *(const float4*)(keys + h0);
            kq1 = *(const float4*)(keys + h1);
            vq0 = *(const float4*)(values + h0);
            vq1 = *(const float4*)(values + h1);
            mk0 = mrow[nn]; mk1 = mrow[nn + 1];
        }
        __syncthreads();
        // fragments + MFMA: D[m][d] += A(V^T) * B(fK)
        const f16x8 afr = lds_load8(&VT[buf][wave * 16 + l15][quad * 8]);
        #pragma unroll
        for (int dt = 0; dt < 4; ++dt) {
            const f16x8 bfr = lds_load8(&KT[buf][dt * 16 + l15][quad * 8]);
            acc[dt] = __builtin_amdgcn_mfma_f32_16x16x32_f16(afr, bfr, acc[dt], 0, 0, 0);
        }
    }

    // KV output: D row = m = 16*wave + 4*quad + reg, col = d = 16*dt + l15
    float* kvb = kv + (size_t)bh * 4096;
    #pragma unroll
    for (int dt = 0; dt < 4; ++dt) {
        #pragma unroll
        for (int reg = 0; reg < 4; ++reg) {
            const int m = wave * 16 + quad * 4 + reg;
            atomicAdd(kvb + m * 64 + dt * 16 + l15, acc[dt][reg]);
        }
    }
    // Ksum: reduce over p within wave (lanes sharing c), then across waves via LDS
    #pragma unroll
    for (int dd = 0; dd < 4; ++dd) {
        float v = ksacc[dd];
        v += __shfl_xor(v, 16);
        v += __shfl_xor(v, 32);
        if (lane < 16) Ksw[wave][lane * 4 + dd] = v;
    }
    __syncthreads();
    if (t < 64) {
        atomicAdd(ksum + bh * 64 + t, Ksw[0][t] + Ksw[1][t] + Ksw[2][t] + Ksw[3][t]);
    }
}

// ---------------------------------------------------------------------------
// Pass 2 (MFMA): out[n][m] = (sum_d fQ[n][d]*KV[m][d]) / (sum_d fQ[n][d]*Ksum[d] + eps)
// grid (BH, 32), block 256. Block covers 256 n-rows; wave w rows [64w,64w+64).
// B-frags (KV, natural layout) + z-tile (Ksum in col 0) held in registers.
// ---------------------------------------------------------------------------
__global__ __launch_bounds__(256, 2) void out_pass(
    const float* __restrict__ queries,
    const float* __restrict__ kv,
    const float* __restrict__ ksum,
    float* __restrict__ out)
{
    const int bh = blockIdx.x, b = bh >> 3, h = bh & 7;
    const int t = threadIdx.x;
    const int wave = t >> 6, lane = t & 63;
    const int quad = lane >> 4;
    const int l15 = lane & 15;
    const int n0 = blockIdx.y * 256;

    __shared__ f16 Qsh[256][68];   // [n][d] pitch 136B
    __shared__ f16 KVh[64][68];    // [m][d]
    __shared__ float Ksh[64];

    // stage KV (fp32 ws -> fp16 LDS, natural [m][d] layout)
    #pragma unroll
    for (int l = 0; l < 4; ++l) {
        const int idx = t + l * 256;
        const int m = idx >> 4, cc = idx & 15;
        const float4 v = *(const float4*)(kv + (size_t)bh * 4096 + m * 64 + cc * 4);
        *(unsigned long long*)&KVh[m][cc * 4] = pack4(v.x, v.y, v.z, v.w);
    }
    if (t < 64) Ksh[t] = ksum[bh * 64 + t];

    // stage fQ rows
    #pragma unroll
    for (int l = 0; l < 16; ++l) {
        const int idx = t + l * 256;
        const int r = idx >> 4, cc = idx & 15;
        const int nn = n0 + r;
        const float4 q = *(const float4*)(queries + ((size_t)((b * N + nn) * H + h)) * 64 + cc * 4);
        *(unsigned long long*)&Qsh[r][cc * 4] =
            pack4(featmap(q.x), featmap(q.y), featmap(q.z), featmap(q.w));
    }
    __syncthreads();

    // B-frags in registers: KV tiles [mt][kstep] + z-tile (Ksum in col 0)
    f16x8 bfr[4][2];
    #pragma unroll
    for (int mt = 0; mt < 4; ++mt)
        #pragma unroll
        for (int ks = 0; ks < 2; ++ks)
            bfr[mt][ks] = lds_load8(&KVh[mt * 16 + l15][ks * 32 + quad * 8]);
    f16x8 bz[2];
    #pragma unroll
    for (int ks = 0; ks < 2; ++ks) {
        #pragma unroll
        for (int j = 0; j < 8; ++j) {
            const float kval = Ksh[ks * 32 + quad * 8 + j];
            bz[ks][j] = (l15 == 0) ? (f16)kval : (f16)0.f;
        }
    }

    #pragma unroll
    for (int nt = 0; nt < 4; ++nt) {
        const int r0 = wave * 64 + nt * 16;
        f32x4 acc[4];
        #pragma unroll
        for (int i = 0; i < 4; ++i) acc[i] = (f32x4){0.f, 0.f, 0.f, 0.f};
        f32x4 az = (f32x4){0.f, 0.f, 0.f, 0.f};

        #pragma unroll
        for (int ks = 0; ks < 2; ++ks) {
            const f16x8 afr = lds_load8(&Qsh[r0 + l15][ks * 32 + quad * 8]);
            #pragma unroll
            for (int mt = 0; mt < 4; ++mt)
                acc[mt] = __builtin_amdgcn_mfma_f32_16x16x32_f16(afr, bfr[mt][ks], acc[mt], 0, 0, 0);
            az = __builtin_amdgcn_mfma_f32_16x16x32_f16(afr, bz[ks], az, 0, 0, 0);
        }

        // epilogue: den sits in col 0 (lane&15==0) of az; broadcast within quad
        #pragma unroll
        for (int reg = 0; reg < 4; ++reg) {
            const float den = __shfl(az[reg], lane & 48);
            const float zin = 1.0f / (den + EPSF);
            const int nn = n0 + r0 + quad * 4 + reg;
            float* op = out + ((size_t)((b * N + nn) * H + h)) * 64 + l15;
            #pragma unroll
            for (int mt = 0; mt < 4; ++mt)
                op[mt * 16] = acc[mt][reg] * zin;
        }
    }
}

extern "C" void kernel_launch(void* const* d_in, const int* in_sizes, int n_in,
                              void* d_out, int out_size, void* d_ws, size_t ws_size,
                              hipStream_t stream)
{
    const float* q    = (const float*)d_in[0];
    const float* k    = (const float*)d_in[1];
    const float* v    = (const float*)d_in[2];
    const float* mask = (const float*)d_in[3];
    float* out = (float*)d_out;

    float* kv = (float*)d_ws;                  // [BH][64][64]
    float* ks = kv + (size_t)BH * 64 * 64;     // [BH][64]

    hipMemsetAsync(d_ws, 0, (size_t)(BH * 64 * 64 + BH * 64) * sizeof(float), stream);
    kv_pass<<<dim3(BH, S1), 256, 0, stream>>>(k, v, mask, kv, ks);
    out_pass<<<dim3(BH, 32), 256, 0, stream>>>(q, kv, ks, out);
}